// Round 4
// baseline (422.896 us; speedup 1.0000x reference)
//
#include <hip/hip_runtime.h>
#include <hip/hip_bf16.h>

// Problem constants
#define BDIM 8
#define TDIM 256
#define UDIM 64
#define HDIM 640
#define VDIM 1024
#define MDIM (BDIM * TDIM * UDIM)   // 131072

// GEMM tiling
#define BM 256
#define BN 256
#define BK 32
#define NT (HDIM / BK)              // 20 K-tiles
#define NBUF 4                      // pipeline depth 3 + compute buffer

typedef __attribute__((ext_vector_type(8))) short short8;   // 8 bf16 (16B)
typedef __attribute__((ext_vector_type(4))) float f32x4;

__device__ __forceinline__ ushort f2bf(float x) {
    union { float f; unsigned int u; } v; v.f = x;
    unsigned int r = (v.u + 0x7fffu + ((v.u >> 16) & 1u)) >> 16;  // RNE
    return (ushort)r;
}

// Prep 1: W (V x H fp32) -> bf16
__global__ void cvt_w_kernel(const float* __restrict__ W, ushort* __restrict__ Wb) {
    int i = (blockIdx.x * 256 + threadIdx.x) * 4;
    f32x4 w = *(const f32x4*)(W + i);
    ushort4 o;
    o.x = f2bf(w[0]); o.y = f2bf(w[1]); o.z = f2bf(w[2]); o.w = f2bf(w[3]);
    *(ushort4*)(Wb + i) = o;
}

// Prep 2: h[m][k] = relu(f[b][t][k] + p[b][u][k]) as bf16
__global__ __launch_bounds__(256) void build_h_kernel(
    const float* __restrict__ f, const float* __restrict__ p,
    ushort* __restrict__ h)
{
    const int tid = threadIdx.x;
    const int row = (blockIdx.x << 5) + (tid >> 3);
    const int j0  = tid & 7;
    const int b = row >> 14;
    const int t = (row >> 6) & (TDIM - 1);
    const int u = row & (UDIM - 1);
    const float* frow = f + (size_t)(b * TDIM + t) * HDIM;
    const float* prow = p + (size_t)(b * UDIM + u) * HDIM;
    ushort* hrow = h + (size_t)row * HDIM;
    #pragma unroll
    for (int it = 0; it < HDIM / 64; ++it) {
        const int k = (j0 + it * 8) * 8;
        f32x4 f0 = *(const f32x4*)(frow + k);
        f32x4 f1 = *(const f32x4*)(frow + k + 4);
        f32x4 p0 = *(const f32x4*)(prow + k);
        f32x4 p1 = *(const f32x4*)(prow + k + 4);
        short8 hv;
        #pragma unroll
        for (int e = 0; e < 4; ++e) {
            float a0 = fmaxf(f0[e] + p0[e], 0.0f);
            float a1 = fmaxf(f1[e] + p1[e], 0.0f);
            hv[e]     = (short)f2bf(a0);
            hv[e + 4] = (short)f2bf(a1);
        }
        *(short8*)(hrow + k) = hv;
    }
}

#define GLDS(srcptr, ldsptr)                                                   \
    __builtin_amdgcn_global_load_lds(                                          \
        (const __attribute__((address_space(1))) void*)(srcptr),               \
        (__attribute__((address_space(3))) void*)(ldsptr), 16, 0, 0)

// 256x256 tile, BK=32, 8 waves (2Mx4N). Depth-3 pipeline: 4 LDS buffers
// (128 KB), one barrier per iteration, counted vmcnt(8) (never 0 until tail).
// Tile kt's loads are issued 3 iterations before use -> HBM latency covered.
// WAR safety: STAGE(kt+3) targets buf (kt-1)&3, whose reads completed before
// every wave arrived at this iteration's barrier.
__global__ __launch_bounds__(512) void hgemm256_kernel(
    const ushort* __restrict__ h,     // (M,H) bf16
    const ushort* __restrict__ Wb,    // (V,H) bf16
    const float* __restrict__ bias,   // (V)
    float* __restrict__ out)          // (M,V) fp32
{
    __shared__ ushort Ash[NBUF][BM * BK];   // 4 x 16 KB
    __shared__ ushort Bsh[NBUF][BN * BK];   // 4 x 16 KB

    const int tid  = threadIdx.x;
    const int lane = tid & 63;
    const int wave = tid >> 6;    // 0..7
    const int wm   = wave >> 2;   // 0..1 -> 128-row half
    const int wn   = wave & 3;    // 0..3 -> 64-col quarter

    // Bijective XCD swizzle: 2048 blocks, 2048%8==0. One XCD walks ntiles
    // fast -> A-panel L2-reused 4x, full Wb (1.25MB) L2-resident.
    const int bid   = blockIdx.x;
    const int work  = (bid & 7) * 256 + (bid >> 3);
    const int mtile = work >> 2;
    const int ntile = work & 3;
    const int m0 = mtile * BM;
    const int v0 = ntile * BN;

    const ushort* hbase = h  + (size_t)m0 * HDIM;
    const ushort* wbase = Wb + (size_t)v0 * HDIM;

    // Staging map: c = it*512 + tid; row=c>>2; j=c&3 (16B chunks, 4/row).
    // Linear LDS slot j holds global chunk j^((row>>1)&3) (pre-swizzled src).
    const int row0 = tid >> 2;
    const int j0   = tid & 3;
    const int jg0  = j0 ^ ((row0 >> 1) & 3);
    const size_t soff0 = (size_t)row0 * HDIM + jg0 * 8;   // + kt*BK at use
    const size_t soff1 = soff0 + (size_t)128 * HDIM;      // rows 128..255
    const int u0 = wave * 512;          // ushort idx of wave's slice, round 0
    const int u1 = 4096 + wave * 512;   // round 1

    // Fragment LDS offsets (ushort idx within a buffer), kt-independent:
    int aoff[8], boff[4];
    #pragma unroll
    for (int mi = 0; mi < 8; ++mi) {
        const int r = wm * 128 + mi * 16 + (lane & 15);
        aoff[mi] = (r * 4 + ((lane >> 4) ^ ((r >> 1) & 3))) * 8;
    }
    #pragma unroll
    for (int ni = 0; ni < 4; ++ni) {
        const int r = wn * 64 + ni * 16 + (lane & 15);
        boff[ni] = (r * 4 + ((lane >> 4) ^ ((r >> 1) & 3))) * 8;
    }

    f32x4 acc[8][4];
    #pragma unroll
    for (int i = 0; i < 8; ++i)
        #pragma unroll
        for (int j = 0; j < 4; ++j)
            acc[i][j] = (f32x4)0.0f;

#define STAGE(kt, bf) do {                                                     \
        GLDS(hbase + soff0 + (kt) * BK, &Ash[bf][u0]);                         \
        GLDS(hbase + soff1 + (kt) * BK, &Ash[bf][u1]);                         \
        GLDS(wbase + soff0 + (kt) * BK, &Bsh[bf][u0]);                         \
        GLDS(wbase + soff1 + (kt) * BK, &Bsh[bf][u1]);                         \
    } while (0)

    STAGE(0, 0);
    STAGE(1, 1);
    STAGE(2, 2);

    for (int kt = 0; kt < NT; ++kt) {
        const int bf = kt & (NBUF - 1);
        // Wait for tile kt's 4 loads (issued 3 iterations ago). In-order
        // vmcnt retirement: <=8 outstanding => oldest 4 (tile kt) landed.
        if (kt < NT - 2) {
            asm volatile("s_waitcnt vmcnt(8)" ::: "memory");
        } else if (kt == NT - 2) {
            asm volatile("s_waitcnt vmcnt(4)" ::: "memory");
        } else {
            asm volatile("s_waitcnt vmcnt(0)" ::: "memory");
        }
        __builtin_amdgcn_sched_barrier(0);
        __builtin_amdgcn_s_barrier();           // all waves' tile-kt loads landed
        __builtin_amdgcn_sched_barrier(0);

        // Prefetch tile kt+3 into buf (kt-1)&3 (reads retired pre-barrier).
        if (kt + 3 < NT) STAGE(kt + 3, (kt + 3) & (NBUF - 1));

        const ushort* Ab = &Ash[bf][0];
        const ushort* Bb = &Bsh[bf][0];

        short8 bfr[4];
        #pragma unroll
        for (int ni = 0; ni < 4; ++ni)
            bfr[ni] = *(const short8*)(Bb + boff[ni]);

        __builtin_amdgcn_s_setprio(1);
        #pragma unroll
        for (int mi = 0; mi < 8; ++mi) {
            short8 av = *(const short8*)(Ab + aoff[mi]);
            #pragma unroll
            for (int ni = 0; ni < 4; ++ni)
                acc[mi][ni] = __builtin_amdgcn_mfma_f32_16x16x32_bf16(
                    av, bfr[ni], acc[mi][ni], 0, 0, 0);
        }
        __builtin_amdgcn_s_setprio(0);
        // no second barrier: buffer rotation (NBUF=4 > depth 3) keeps WAR safe
    }
#undef STAGE

    // Epilogue: C/D col = lane&15, row = (lane>>4)*4 + reg
    #pragma unroll
    for (int ni = 0; ni < 4; ++ni) {
        const int col = v0 + wn * 64 + ni * 16 + (lane & 15);
        const float bv = bias[col];
        #pragma unroll
        for (int mi = 0; mi < 8; ++mi) {
            const int rbase = m0 + wm * 128 + mi * 16 + ((lane >> 4) << 2);
            #pragma unroll
            for (int reg = 0; reg < 4; ++reg) {
                out[(size_t)(rbase + reg) * VDIM + col] = acc[mi][ni][reg] + bv;
            }
        }
    }
}

// ---------------- fallback fused kernel (round-1 verified) ----------------
template <bool USE_WB>
__global__ __launch_bounds__(256) void joint_gemm_kernel(
    const float* __restrict__ f, const float* __restrict__ p,
    const float* __restrict__ Wf, const ushort* __restrict__ Wb,
    const float* __restrict__ bias, float* __restrict__ out)
{
    __shared__ ushort Alds[128 * 64];
    __shared__ ushort Blds[128 * 64];

    const int tid  = threadIdx.x;
    const int lane = tid & 63;
    const int wave = tid >> 6;
    const int wm   = wave >> 1;
    const int wn   = wave & 1;

    const int bid   = blockIdx.x;
    const int work  = (bid & 7) * 1024 + (bid >> 3);
    const int mtile = work >> 3;
    const int ntile = work & 7;
    const int m0 = mtile * 128;
    const int v0 = ntile * 128;

    const int b  = m0 >> 14;
    const int t0 = (m0 >> 6) & (TDIM - 1);

    const float*  fbase = f + (size_t)(b * TDIM + t0) * HDIM;
    const float*  pbase = p + (size_t)b * UDIM * HDIM;
    const ushort* wbbase = Wb + (size_t)v0 * HDIM;
    const float*  wfbase = Wf + (size_t)v0 * HDIM;

    f32x4 acc[4][4];
    #pragma unroll
    for (int i = 0; i < 4; ++i)
        #pragma unroll
        for (int j = 0; j < 4; ++j)
            acc[i][j] = (f32x4)0.0f;

    for (int kt = 0; kt < HDIM / 64; ++kt) {
        const int k0 = kt * 64;
        __syncthreads();

        if (USE_WB) {
            #pragma unroll
            for (int it = 0; it < 4; ++it) {
                const int c   = it * 256 + tid;
                const int row = c >> 3;
                const int j   = c & 7;
                const ushort* src = wbbase + row * HDIM + k0 + ((j ^ (row & 7)) << 3);
                GLDS(src, &Blds[(it * 256 + wave * 64) * 8]);
            }
        } else {
            #pragma unroll
            for (int it = 0; it < 4; ++it) {
                const int c   = it * 256 + tid;
                const int row = c >> 3;
                const int j   = c & 7;
                const float* wp = wfbase + row * HDIM + k0 + j * 8;
                f32x4 w0 = *(const f32x4*)wp;
                f32x4 w1 = *(const f32x4*)(wp + 4);
                short8 wv;
                #pragma unroll
                for (int e = 0; e < 4; ++e) {
                    wv[e]     = (short)f2bf(w0[e]);
                    wv[e + 4] = (short)f2bf(w1[e]);
                }
                *(short8*)(&Blds[(row * 8 + (j ^ (row & 7))) * 8]) = wv;
            }
        }

        #pragma unroll
        for (int it = 0; it < 4; ++it) {
            const int c   = it * 256 + tid;
            const int row = c >> 3;
            const int j   = c & 7;
            const float* fp_ = fbase + (row >> 6) * HDIM + k0 + j * 8;
            const float* pp_ = pbase + (row & 63) * HDIM + k0 + j * 8;
            f32x4 f0 = *(const f32x4*)fp_;
            f32x4 f1 = *(const f32x4*)(fp_ + 4);
            f32x4 p0 = *(const f32x4*)pp_;
            f32x4 p1 = *(const f32x4*)(pp_ + 4);
            short8 hv;
            #pragma unroll
            for (int e = 0; e < 4; ++e) {
                float a0 = fmaxf(f0[e] + p0[e], 0.0f);
                float a1 = fmaxf(f1[e] + p1[e], 0.0f);
                hv[e]     = (short)f2bf(a0);
                hv[e + 4] = (short)f2bf(a1);
            }
            *(short8*)(&Alds[(row * 8 + (j ^ (row & 7))) * 8]) = hv;
        }

        __syncthreads();

        #pragma unroll
        for (int ks = 0; ks < 2; ++ks) {
            short8 afr[4], bfr[4];
            #pragma unroll
            for (int mi = 0; mi < 4; ++mi) {
                const int r = wm * 64 + mi * 16 + (lane & 15);
                const int j = ks * 4 + (lane >> 4);
                afr[mi] = *(const short8*)(&Alds[(r * 8 + (j ^ (r & 7))) * 8]);
            }
            #pragma unroll
            for (int ni = 0; ni < 4; ++ni) {
                const int r = wn * 64 + ni * 16 + (lane & 15);
                const int j = ks * 4 + (lane >> 4);
                bfr[ni] = *(const short8*)(&Blds[(r * 8 + (j ^ (r & 7))) * 8]);
            }
            #pragma unroll
            for (int mi = 0; mi < 4; ++mi)
                #pragma unroll
                for (int ni = 0; ni < 4; ++ni)
                    acc[mi][ni] = __builtin_amdgcn_mfma_f32_16x16x32_bf16(
                        afr[mi], bfr[ni], acc[mi][ni], 0, 0, 0);
        }
    }

    #pragma unroll
    for (int ni = 0; ni < 4; ++ni) {
        const int col = v0 + wn * 64 + ni * 16 + (lane & 15);
        const float bv = bias[col];
        #pragma unroll
        for (int mi = 0; mi < 4; ++mi) {
            const int rbase = m0 + wm * 64 + mi * 16 + ((lane >> 4) << 2);
            #pragma unroll
            for (int reg = 0; reg < 4; ++reg) {
                out[(size_t)(rbase + reg) * VDIM + col] = acc[mi][ni][reg] + bv;
            }
        }
    }
}

extern "C" void kernel_launch(void* const* d_in, const int* in_sizes, int n_in,
                              void* d_out, int out_size, void* d_ws, size_t ws_size,
                              hipStream_t stream) {
    const float* f    = (const float*)d_in[0];   // (8,256,640)
    const float* p    = (const float*)d_in[1];   // (8,64,640)
    const float* W    = (const float*)d_in[2];   // (1024,640)
    const float* bias = (const float*)d_in[3];   // (1024)
    float* out = (float*)d_out;                  // (8,256,64,1024) fp32

    const size_t wb_bytes = (size_t)VDIM * HDIM * sizeof(ushort);   // 1.25 MB
    const size_t h_bytes  = (size_t)MDIM * HDIM * sizeof(ushort);   // 160 MB

    if (ws_size >= wb_bytes + h_bytes) {
        ushort* Wb = (ushort*)d_ws;
        ushort* h  = (ushort*)((char*)d_ws + wb_bytes);
        cvt_w_kernel<<<(VDIM * HDIM) / 1024, 256, 0, stream>>>(W, Wb);
        build_h_kernel<<<MDIM / 32, 256, 0, stream>>>(f, p, h);
        const int grid = (MDIM / BM) * (VDIM / BN);   // 2048
        hgemm256_kernel<<<grid, 512, 0, stream>>>(h, Wb, bias, out);
    } else if (ws_size >= wb_bytes) {
        ushort* Wb = (ushort*)d_ws;
        cvt_w_kernel<<<(VDIM * HDIM) / 1024, 256, 0, stream>>>(W, Wb);
        joint_gemm_kernel<true><<<(MDIM / 128) * (VDIM / 128), 256, 0, stream>>>(
            f, p, W, Wb, bias, out);
    } else {
        joint_gemm_kernel<false><<<(MDIM / 128) * (VDIM / 128), 256, 0, stream>>>(
            f, p, W, nullptr, bias, out);
    }
}

// Round 5
// 385.777 us; speedup vs baseline: 1.0962x; 1.0962x over previous
//
#include <hip/hip_runtime.h>
#include <hip/hip_bf16.h>

// Problem constants
#define BDIM 8
#define TDIM 256
#define UDIM 64
#define HDIM 640
#define VDIM 1024
#define MDIM (BDIM * TDIM * UDIM)   // 131072

// 8-phase GEMM tiling (m201 template geometry)
#define BM 256
#define BN 256
#define BK 64
#define NT64 (HDIM / BK)            // 10 K-tiles

typedef __attribute__((ext_vector_type(8))) short short8;   // 8 bf16 (16B)
typedef __attribute__((ext_vector_type(4))) float f32x4;

__device__ __forceinline__ ushort f2bf(float x) {
    union { float f; unsigned int u; } v; v.f = x;
    unsigned int r = (v.u + 0x7fffu + ((v.u >> 16) & 1u)) >> 16;  // RNE
    return (ushort)r;
}

// Prep 1: W (V x H fp32) -> bf16
__global__ void cvt_w_kernel(const float* __restrict__ W, ushort* __restrict__ Wb) {
    int i = (blockIdx.x * 256 + threadIdx.x) * 4;
    f32x4 w = *(const f32x4*)(W + i);
    ushort4 o;
    o.x = f2bf(w[0]); o.y = f2bf(w[1]); o.z = f2bf(w[2]); o.w = f2bf(w[3]);
    *(ushort4*)(Wb + i) = o;
}

// Prep 2: h[m][k] = relu(f[b][t][k] + p[b][u][k]) as bf16
__global__ __launch_bounds__(256) void build_h_kernel(
    const float* __restrict__ f, const float* __restrict__ p,
    ushort* __restrict__ h)
{
    const int tid = threadIdx.x;
    const int row = (blockIdx.x << 5) + (tid >> 3);
    const int j0  = tid & 7;
    const int b = row >> 14;
    const int t = (row >> 6) & (TDIM - 1);
    const int u = row & (UDIM - 1);
    const float* frow = f + (size_t)(b * TDIM + t) * HDIM;
    const float* prow = p + (size_t)(b * UDIM + u) * HDIM;
    ushort* hrow = h + (size_t)row * HDIM;
    #pragma unroll
    for (int it = 0; it < HDIM / 64; ++it) {
        const int k = (j0 + it * 8) * 8;
        f32x4 f0 = *(const f32x4*)(frow + k);
        f32x4 f1 = *(const f32x4*)(frow + k + 4);
        f32x4 p0 = *(const f32x4*)(prow + k);
        f32x4 p1 = *(const f32x4*)(prow + k + 4);
        short8 hv;
        #pragma unroll
        for (int e = 0; e < 4; ++e) {
            float a0 = fmaxf(f0[e] + p0[e], 0.0f);
            float a1 = fmaxf(f1[e] + p1[e], 0.0f);
            hv[e]     = (short)f2bf(a0);
            hv[e + 4] = (short)f2bf(a1);
        }
        *(short8*)(hrow + k) = hv;
    }
}

#define GLDS(srcptr, ldsptr)                                                   \
    __builtin_amdgcn_global_load_lds(                                          \
        (const __attribute__((address_space(1))) void*)(srcptr),               \
        (__attribute__((address_space(3))) void*)(ldsptr), 16, 0, 0)

// ============================ 8-phase GEMM ============================
// 256x256 tile, BK=64, 8 waves (2Mx4N), 512 threads. LDS = 2 dbuf x
// {A,B} x 2 K-halves x (256x32 bf16 = 16 KB) = 128 KB.
// Per K-tile: 4 phases (ks, mh). Each phase: {ds_read frags || issue one
// 16KB half prefetch -> barrier -> lgkmcnt(0) -> 16 MFMA (setprio) -> barrier}.
//
// vmcnt ledger (per wave; each STG = 2 gload_lds ops), steady state at tile t:
//   start-of-t:   flying = Kh1[t] (4)                      [Kh0[t] landed]
//   P0 issues A-Kh0[t+1] (6), P1 issues B-Kh0[t+1] (8)
//   end-P1: vmcnt(4) retires Kh1[t]   -> P2/P3 reads safe; flying Kh0[t+1]
//   P2 issues A-Kh1[t+1] (6), P3 issues B-Kh1[t+1] (8)
//   end-P3: vmcnt(4) retires Kh0[t+1] -> next tile P0/P1 safe; flying Kh1[t+1]
// Lead time = 3 phases per half; never drains except last tile's end-P1.
// WAR: staging dbuf e during tile t is safe — e was last read in tile t-1,
// whose per-wave reads completed (lgkmcnt) before the boundary barrier.
// [256][32] LDS layout: frag ds_read_b128 is bank-even (8 lanes/bank = b128
// floor) and gload_lds dest is linear -> no swizzle needed on either side.
__global__ __launch_bounds__(512) void hgemm8p_kernel(
    const ushort* __restrict__ h,     // (M,H) bf16
    const ushort* __restrict__ Wb,    // (V,H) bf16
    const float* __restrict__ bias,   // (V)
    float* __restrict__ out)          // (M,V) fp32
{
    __shared__ ushort Ash[2][2][BM * 32];   // [dbuf][khalf][256*32] 16 KB each
    __shared__ ushort Bsh[2][2][BN * 32];

    const int tid  = threadIdx.x;
    const int lane = tid & 63;
    const int wave = tid >> 6;    // 0..7
    const int wm   = wave >> 2;   // 0..1 -> 128-row half
    const int wn   = wave & 3;    // 0..3 -> 64-col quarter

    // Bijective XCD swizzle: 2048 blocks (2048%8==0); each XCD walks ntiles
    // fast -> A-panel L2-reused 4x, Wb (1.25MB) L2-resident.
    const int bid   = blockIdx.x;
    const int work  = (bid & 7) * 256 + (bid >> 3);
    const int mtile = work >> 2;
    const int ntile = work & 3;
    const int m0 = mtile * BM;
    const int v0 = ntile * BN;

    const ushort* hbase = h  + (size_t)m0 * HDIM;
    const ushort* wbase = Wb + (size_t)v0 * HDIM;

    // Staging map (per half, 1024 chunks of 16B, 2 instr/thread):
    // chunk c = i*512 + tid; row = c>>2; j = c&3. Linear LDS, linear source.
    const int r0 = tid >> 2;
    const int j0 = tid & 3;
    const size_t soff0 = (size_t)r0 * HDIM + j0 * 8;   // + t*64 + kh*32
    const size_t soff1 = soff0 + (size_t)128 * HDIM;   // rows 128..255
    const int u0 = wave * 512;          // ushort idx of wave slice, instr 0
    const int u1 = 4096 + wave * 512;   // instr 1

    // Fragment offsets within a [256][32] K-half (ushort idx):
    int aoff[8], boff[4];
    #pragma unroll
    for (int mi = 0; mi < 8; ++mi) {
        const int r = wm * 128 + mi * 16 + (lane & 15);
        aoff[mi] = r * 32 + (lane >> 4) * 8;
    }
    #pragma unroll
    for (int ni = 0; ni < 4; ++ni) {
        const int r = wn * 64 + ni * 16 + (lane & 15);
        boff[ni] = r * 32 + (lane >> 4) * 8;
    }

    f32x4 acc[8][4];
    #pragma unroll
    for (int i = 0; i < 8; ++i)
        #pragma unroll
        for (int j = 0; j < 4; ++j)
            acc[i][j] = (f32x4)0.0f;

#define STG(dsthalf, srcbase, koff) do {                                       \
        GLDS((srcbase) + soff0 + (koff), &(dsthalf)[u0]);                      \
        GLDS((srcbase) + soff1 + (koff), &(dsthalf)[u1]);                      \
    } while (0)

    // Prologue: tile 0 (A-Kh0, B-Kh0, A-Kh1, B-Kh1); keep Kh1 in flight.
    STG(Ash[0][0], hbase, 0);
    STG(Bsh[0][0], wbase, 0);
    STG(Ash[0][1], hbase, 32);
    STG(Bsh[0][1], wbase, 32);
    asm volatile("s_waitcnt vmcnt(4)" ::: "memory");
    __builtin_amdgcn_sched_barrier(0);
    __builtin_amdgcn_s_barrier();

    #pragma unroll 2
    for (int t = 0; t < NT64; ++t) {
        const int d = t & 1;
        const int e = d ^ 1;
        const bool pf = (t + 1 < NT64);
        const int knext = (t + 1) * BK;
        short8 afr[4], bfr[4];

        // ---------- P0: ks=0, mi 0..3 ----------
        #pragma unroll
        for (int n = 0; n < 4; ++n) bfr[n] = *(const short8*)(&Bsh[d][0][boff[n]]);
        #pragma unroll
        for (int q = 0; q < 4; ++q) afr[q] = *(const short8*)(&Ash[d][0][aoff[q]]);
        if (pf) STG(Ash[e][0], hbase, knext);
        __builtin_amdgcn_s_barrier();
        asm volatile("s_waitcnt lgkmcnt(0)" ::: "memory");
        __builtin_amdgcn_sched_barrier(0);
        __builtin_amdgcn_s_setprio(1);
        #pragma unroll
        for (int q = 0; q < 4; ++q)
            #pragma unroll
            for (int n = 0; n < 4; ++n)
                acc[q][n] = __builtin_amdgcn_mfma_f32_16x16x32_bf16(
                    afr[q], bfr[n], acc[q][n], 0, 0, 0);
        __builtin_amdgcn_s_setprio(0);
        __builtin_amdgcn_sched_barrier(0);
        __builtin_amdgcn_s_barrier();

        // ---------- P1: ks=0, mi 4..7 ----------
        #pragma unroll
        for (int q = 0; q < 4; ++q) afr[q] = *(const short8*)(&Ash[d][0][aoff[4 + q]]);
        if (pf) STG(Bsh[e][0], wbase, knext);
        __builtin_amdgcn_s_barrier();
        asm volatile("s_waitcnt lgkmcnt(0)" ::: "memory");
        __builtin_amdgcn_sched_barrier(0);
        __builtin_amdgcn_s_setprio(1);
        #pragma unroll
        for (int q = 0; q < 4; ++q)
            #pragma unroll
            for (int n = 0; n < 4; ++n)
                acc[4 + q][n] = __builtin_amdgcn_mfma_f32_16x16x32_bf16(
                    afr[q], bfr[n], acc[4 + q][n], 0, 0, 0);
        __builtin_amdgcn_s_setprio(0);
        __builtin_amdgcn_sched_barrier(0);
        if (pf) { asm volatile("s_waitcnt vmcnt(4)" ::: "memory"); }
        else    { asm volatile("s_waitcnt vmcnt(0)" ::: "memory"); }
        __builtin_amdgcn_sched_barrier(0);
        __builtin_amdgcn_s_barrier();

        // ---------- P2: ks=1, mi 0..3 ----------
        #pragma unroll
        for (int n = 0; n < 4; ++n) bfr[n] = *(const short8*)(&Bsh[d][1][boff[n]]);
        #pragma unroll
        for (int q = 0; q < 4; ++q) afr[q] = *(const short8*)(&Ash[d][1][aoff[q]]);
        if (pf) STG(Ash[e][1], hbase, knext + 32);
        __builtin_amdgcn_s_barrier();
        asm volatile("s_waitcnt lgkmcnt(0)" ::: "memory");
        __builtin_amdgcn_sched_barrier(0);
        __builtin_amdgcn_s_setprio(1);
        #pragma unroll
        for (int q = 0; q < 4; ++q)
            #pragma unroll
            for (int n = 0; n < 4; ++n)
                acc[q][n] = __builtin_amdgcn_mfma_f32_16x16x32_bf16(
                    afr[q], bfr[n], acc[q][n], 0, 0, 0);
        __builtin_amdgcn_s_setprio(0);
        __builtin_amdgcn_sched_barrier(0);
        __builtin_amdgcn_s_barrier();

        // ---------- P3: ks=1, mi 4..7 ----------
        #pragma unroll
        for (int q = 0; q < 4; ++q) afr[q] = *(const short8*)(&Ash[d][1][aoff[4 + q]]);
        if (pf) STG(Bsh[e][1], wbase, knext + 32);
        __builtin_amdgcn_s_barrier();
        asm volatile("s_waitcnt lgkmcnt(0)" ::: "memory");
        __builtin_amdgcn_sched_barrier(0);
        __builtin_amdgcn_s_setprio(1);
        #pragma unroll
        for (int q = 0; q < 4; ++q)
            #pragma unroll
            for (int n = 0; n < 4; ++n)
                acc[4 + q][n] = __builtin_amdgcn_mfma_f32_16x16x32_bf16(
                    afr[q], bfr[n], acc[4 + q][n], 0, 0, 0);
        __builtin_amdgcn_s_setprio(0);
        __builtin_amdgcn_sched_barrier(0);
        if (pf) {
            asm volatile("s_waitcnt vmcnt(4)" ::: "memory");
            __builtin_amdgcn_sched_barrier(0);
        }
        __builtin_amdgcn_s_barrier();
    }
#undef STG

    // Epilogue: C/D col = lane&15, row = (lane>>4)*4 + reg
    #pragma unroll
    for (int ni = 0; ni < 4; ++ni) {
        const int col = v0 + wn * 64 + ni * 16 + (lane & 15);
        const float bv = bias[col];
        #pragma unroll
        for (int mi = 0; mi < 8; ++mi) {
            const int rbase = m0 + wm * 128 + mi * 16 + ((lane >> 4) << 2);
            #pragma unroll
            for (int reg = 0; reg < 4; ++reg) {
                out[(size_t)(rbase + reg) * VDIM + col] = acc[mi][ni][reg] + bv;
            }
        }
    }
}

// ---------------- fallback fused kernel (round-1 verified) ----------------
template <bool USE_WB>
__global__ __launch_bounds__(256) void joint_gemm_kernel(
    const float* __restrict__ f, const float* __restrict__ p,
    const float* __restrict__ Wf, const ushort* __restrict__ Wb,
    const float* __restrict__ bias, float* __restrict__ out)
{
    __shared__ ushort Alds[128 * 64];
    __shared__ ushort Blds[128 * 64];

    const int tid  = threadIdx.x;
    const int lane = tid & 63;
    const int wave = tid >> 6;
    const int wm   = wave >> 1;
    const int wn   = wave & 1;

    const int bid   = blockIdx.x;
    const int work  = (bid & 7) * 1024 + (bid >> 3);
    const int mtile = work >> 3;
    const int ntile = work & 7;
    const int m0 = mtile * 128;
    const int v0 = ntile * 128;

    const int b  = m0 >> 14;
    const int t0 = (m0 >> 6) & (TDIM - 1);

    const float*  fbase = f + (size_t)(b * TDIM + t0) * HDIM;
    const float*  pbase = p + (size_t)b * UDIM * HDIM;
    const ushort* wbbase = Wb + (size_t)v0 * HDIM;
    const float*  wfbase = Wf + (size_t)v0 * HDIM;

    f32x4 acc[4][4];
    #pragma unroll
    for (int i = 0; i < 4; ++i)
        #pragma unroll
        for (int j = 0; j < 4; ++j)
            acc[i][j] = (f32x4)0.0f;

    for (int kt = 0; kt < HDIM / 64; ++kt) {
        const int k0 = kt * 64;
        __syncthreads();

        if (USE_WB) {
            #pragma unroll
            for (int it = 0; it < 4; ++it) {
                const int c   = it * 256 + tid;
                const int row = c >> 3;
                const int j   = c & 7;
                const ushort* src = wbbase + row * HDIM + k0 + ((j ^ (row & 7)) << 3);
                GLDS(src, &Blds[(it * 256 + wave * 64) * 8]);
            }
        } else {
            #pragma unroll
            for (int it = 0; it < 4; ++it) {
                const int c   = it * 256 + tid;
                const int row = c >> 3;
                const int j   = c & 7;
                const float* wp = wfbase + row * HDIM + k0 + j * 8;
                f32x4 w0 = *(const f32x4*)wp;
                f32x4 w1 = *(const f32x4*)(wp + 4);
                short8 wv;
                #pragma unroll
                for (int e = 0; e < 4; ++e) {
                    wv[e]     = (short)f2bf(w0[e]);
                    wv[e + 4] = (short)f2bf(w1[e]);
                }
                *(short8*)(&Blds[(row * 8 + (j ^ (row & 7))) * 8]) = wv;
            }
        }

        #pragma unroll
        for (int it = 0; it < 4; ++it) {
            const int c   = it * 256 + tid;
            const int row = c >> 3;
            const int j   = c & 7;
            const float* fp_ = fbase + (row >> 6) * HDIM + k0 + j * 8;
            const float* pp_ = pbase + (row & 63) * HDIM + k0 + j * 8;
            f32x4 f0 = *(const f32x4*)fp_;
            f32x4 f1 = *(const f32x4*)(fp_ + 4);
            f32x4 p0 = *(const f32x4*)pp_;
            f32x4 p1 = *(const f32x4*)(pp_ + 4);
            short8 hv;
            #pragma unroll
            for (int e = 0; e < 4; ++e) {
                float a0 = fmaxf(f0[e] + p0[e], 0.0f);
                float a1 = fmaxf(f1[e] + p1[e], 0.0f);
                hv[e]     = (short)f2bf(a0);
                hv[e + 4] = (short)f2bf(a1);
            }
            *(short8*)(&Alds[(row * 8 + (j ^ (row & 7))) * 8]) = hv;
        }

        __syncthreads();

        #pragma unroll
        for (int ks = 0; ks < 2; ++ks) {
            short8 afr[4], bfr[4];
            #pragma unroll
            for (int mi = 0; mi < 4; ++mi) {
                const int r = wm * 64 + mi * 16 + (lane & 15);
                const int j = ks * 4 + (lane >> 4);
                afr[mi] = *(const short8*)(&Alds[(r * 8 + (j ^ (r & 7))) * 8]);
            }
            #pragma unroll
            for (int ni = 0; ni < 4; ++ni) {
                const int r = wn * 64 + ni * 16 + (lane & 15);
                const int j = ks * 4 + (lane >> 4);
                bfr[ni] = *(const short8*)(&Blds[(r * 8 + (j ^ (r & 7))) * 8]);
            }
            #pragma unroll
            for (int mi = 0; mi < 4; ++mi)
                #pragma unroll
                for (int ni = 0; ni < 4; ++ni)
                    acc[mi][ni] = __builtin_amdgcn_mfma_f32_16x16x32_bf16(
                        afr[mi], bfr[ni], acc[mi][ni], 0, 0, 0);
        }
    }

    #pragma unroll
    for (int ni = 0; ni < 4; ++ni) {
        const int col = v0 + wn * 64 + ni * 16 + (lane & 15);
        const float bv = bias[col];
        #pragma unroll
        for (int mi = 0; mi < 4; ++mi) {
            const int rbase = m0 + wm * 64 + mi * 16 + ((lane >> 4) << 2);
            #pragma unroll
            for (int reg = 0; reg < 4; ++reg) {
                out[(size_t)(rbase + reg) * VDIM + col] = acc[mi][ni][reg] + bv;
            }
        }
    }
}

extern "C" void kernel_launch(void* const* d_in, const int* in_sizes, int n_in,
                              void* d_out, int out_size, void* d_ws, size_t ws_size,
                              hipStream_t stream) {
    const float* f    = (const float*)d_in[0];   // (8,256,640)
    const float* p    = (const float*)d_in[1];   // (8,64,640)
    const float* W    = (const float*)d_in[2];   // (1024,640)
    const float* bias = (const float*)d_in[3];   // (1024)
    float* out = (float*)d_out;                  // (8,256,64,1024) fp32

    const size_t wb_bytes = (size_t)VDIM * HDIM * sizeof(ushort);   // 1.25 MB
    const size_t h_bytes  = (size_t)MDIM * HDIM * sizeof(ushort);   // 160 MB

    if (ws_size >= wb_bytes + h_bytes) {
        ushort* Wb = (ushort*)d_ws;
        ushort* h  = (ushort*)((char*)d_ws + wb_bytes);
        cvt_w_kernel<<<(VDIM * HDIM) / 1024, 256, 0, stream>>>(W, Wb);
        build_h_kernel<<<MDIM / 32, 256, 0, stream>>>(f, p, h);
        const int grid = (MDIM / BM) * (VDIM / BN);   // 2048
        hgemm8p_kernel<<<grid, 512, 0, stream>>>(h, Wb, bias, out);
    } else if (ws_size >= wb_bytes) {
        ushort* Wb = (ushort*)d_ws;
        cvt_w_kernel<<<(VDIM * HDIM) / 1024, 256, 0, stream>>>(W, Wb);
        joint_gemm_kernel<true><<<(MDIM / 128) * (VDIM / 128), 256, 0, stream>>>(
            f, p, W, Wb, bias, out);
    } else {
        joint_gemm_kernel<false><<<(MDIM / 128) * (VDIM / 128), 256, 0, stream>>>(
            f, p, W, nullptr, bias, out);
    }
}

// Round 6
// 352.025 us; speedup vs baseline: 1.2013x; 1.0959x over previous
//
#include <hip/hip_runtime.h>
#include <hip/hip_bf16.h>

// Problem constants
#define BDIM 8
#define TDIM 256
#define UDIM 64
#define HDIM 640
#define VDIM 1024
#define MDIM (BDIM * TDIM * UDIM)   // 131072

// GEMM tiling: occupancy-first. 128x128 tile, BK=32, 4 waves, 32KB LDS
// -> 4 blocks/CU co-resident (the m97/m114 implicit-overlap regime).
#define BM 128
#define BN 128
#define BK 32
#define NT (HDIM / BK)              // 20 K-tiles

typedef __attribute__((ext_vector_type(8))) short short8;   // 8 bf16 (16B)
typedef __attribute__((ext_vector_type(4))) float f32x4;

__device__ __forceinline__ ushort f2bf(float x) {
    union { float f; unsigned int u; } v; v.f = x;
    unsigned int r = (v.u + 0x7fffu + ((v.u >> 16) & 1u)) >> 16;  // RNE
    return (ushort)r;
}

// Prep 1: W (V x H fp32) -> bf16
__global__ void cvt_w_kernel(const float* __restrict__ W, ushort* __restrict__ Wb) {
    int i = (blockIdx.x * 256 + threadIdx.x) * 4;
    f32x4 w = *(const f32x4*)(W + i);
    ushort4 o;
    o.x = f2bf(w[0]); o.y = f2bf(w[1]); o.z = f2bf(w[2]); o.w = f2bf(w[3]);
    *(ushort4*)(Wb + i) = o;
}

// Prep 2: h[m][k] = relu(f[b][t][k] + p[b][u][k]) as bf16
__global__ __launch_bounds__(256) void build_h_kernel(
    const float* __restrict__ f, const float* __restrict__ p,
    ushort* __restrict__ h)
{
    const int tid = threadIdx.x;
    const int row = (blockIdx.x << 5) + (tid >> 3);
    const int j0  = tid & 7;
    const int b = row >> 14;
    const int t = (row >> 6) & (TDIM - 1);
    const int u = row & (UDIM - 1);
    const float* frow = f + (size_t)(b * TDIM + t) * HDIM;
    const float* prow = p + (size_t)(b * UDIM + u) * HDIM;
    ushort* hrow = h + (size_t)row * HDIM;
    #pragma unroll
    for (int it = 0; it < HDIM / 64; ++it) {
        const int k = (j0 + it * 8) * 8;
        f32x4 f0 = *(const f32x4*)(frow + k);
        f32x4 f1 = *(const f32x4*)(frow + k + 4);
        f32x4 p0 = *(const f32x4*)(prow + k);
        f32x4 p1 = *(const f32x4*)(prow + k + 4);
        short8 hv;
        #pragma unroll
        for (int e = 0; e < 4; ++e) {
            float a0 = fmaxf(f0[e] + p0[e], 0.0f);
            float a1 = fmaxf(f1[e] + p1[e], 0.0f);
            hv[e]     = (short)f2bf(a0);
            hv[e + 4] = (short)f2bf(a1);
        }
        *(short8*)(hrow + k) = hv;
    }
}

#define GLDS(srcptr, ldsptr)                                                   \
    __builtin_amdgcn_global_load_lds(                                          \
        (const __attribute__((address_space(1))) void*)(srcptr),               \
        (__attribute__((address_space(3))) void*)(ldsptr), 16, 0, 0)

// 128x128 tile, BK=32, 4 waves (2x2), dbuf-2, counted vmcnt(4), 32KB LDS.
// Swizzle (rounds 3/4 verified, 0 conflicts): 16B-chunk slot = j ^ ((row>>1)&3)
// -> frag-read bank group = 4*(row&1) + slot covers all 8 groups over 8 rows
// (2 lanes/group = free). Staging pre-swizzles the GLOBAL source (rule #21).
//
// Race audit (2 barriers/tile):
//  - STG(t+1) overwrites buf[(t+1)&1], last read during tile t-1; every wave
//    finished those reads (lgkm precedes its MFMAs) before t-1's END barrier,
//    which precedes this STG.  SAFE.
//  - Reads of buf[t&1] follow: own vmcnt(4) retiring tile-t slice + MID
//    barrier (so all waves' slices landed).  SAFE.
// vmcnt ledger: steady outstanding after STG(t+1) = {t:4, t+1:4} -> vmcnt(4)
// retires t, keeps 4 flying across both barriers; drains only at t=NT-1.
__global__ __launch_bounds__(256, 4) void hgemm128_kernel(
    const ushort* __restrict__ h,     // (M,H) bf16
    const ushort* __restrict__ Wb,    // (V,H) bf16
    const float* __restrict__ bias,   // (V)
    float* __restrict__ out)          // (M,V) fp32
{
    __shared__ ushort Ash[2][BM * BK];  // 2 x 8 KB
    __shared__ ushort Bsh[2][BN * BK];  // 2 x 8 KB

    const int tid  = threadIdx.x;
    const int lane = tid & 63;
    const int wave = tid >> 6;   // 0..3
    const int wm   = wave >> 1;  // 0..1 -> 64-row half
    const int wn   = wave & 1;   // 0..1 -> 64-col half

    // Bijective XCD swizzle: 8192 blocks (%8==0). XCD x runs works
    // [x*1024,(x+1)*1024) in order: 8 ntiles of one mtile consecutive ->
    // ~16 mtiles resident per XCD: A panels (2.5MB) + Wb (1.25MB) ~ L2 4MB.
    const int bid   = blockIdx.x;
    const int work  = (bid & 7) * 1024 + (bid >> 3);
    const int mtile = work >> 3;
    const int ntile = work & 7;
    const int m0 = mtile * BM;
    const int v0 = ntile * BN;

    const ushort* hbase = h  + (size_t)m0 * HDIM;
    const ushort* wbase = Wb + (size_t)v0 * HDIM;

    // Staging map: per buffer 512 x 16B chunks, 2 per thread (i=0,1).
    // LDS slot s = i*256+tid: row = s>>2, j = s&3; holds global chunk
    // j ^ ((row>>1)&3).  Dest chunk = i*256 + wave*64 + lane (linear).
    const int r0a = tid >> 2;          // i=0 row
    const int r0b = r0a + 64;          // i=1 row
    const int j0  = tid & 3;
    const size_t sof0 = (size_t)r0a * HDIM + (j0 ^ ((r0a >> 1) & 3)) * 8;
    const size_t sof1 = (size_t)r0b * HDIM + (j0 ^ ((r0b >> 1) & 3)) * 8;
    const int u0 = (wave * 64) * 8;          // ushort idx, i=0 (lane*16B by HW)
    const int u1 = (256 + wave * 64) * 8;    // i=1

    // Fragment offsets (ushort idx within one buffer), kt-independent.
    int aoff[4], boff[4];
    #pragma unroll
    for (int mi = 0; mi < 4; ++mi) {
        const int r = wm * 64 + mi * 16 + (lane & 15);
        aoff[mi] = (r * 4 + ((lane >> 4) ^ ((r >> 1) & 3))) * 8;
    }
    #pragma unroll
    for (int ni = 0; ni < 4; ++ni) {
        const int r = wn * 64 + ni * 16 + (lane & 15);
        boff[ni] = (r * 4 + ((lane >> 4) ^ ((r >> 1) & 3))) * 8;
    }

    f32x4 acc[4][4];
    #pragma unroll
    for (int i = 0; i < 4; ++i)
        #pragma unroll
        for (int j = 0; j < 4; ++j)
            acc[i][j] = (f32x4)0.0f;

#define STG(kt, bf) do {                                                       \
        GLDS(hbase + sof0 + (kt) * BK, &Ash[bf][u0]);                          \
        GLDS(hbase + sof1 + (kt) * BK, &Ash[bf][u1]);                          \
        GLDS(wbase + sof0 + (kt) * BK, &Bsh[bf][u0]);                          \
        GLDS(wbase + sof1 + (kt) * BK, &Bsh[bf][u1]);                          \
    } while (0)

#define TILE(t, d) do {                                                        \
        if ((t) + 1 < NT) {                                                    \
            STG((t) + 1, (d) ^ 1);                                             \
            asm volatile("s_waitcnt vmcnt(4)" ::: "memory");                   \
        } else {                                                               \
            asm volatile("s_waitcnt vmcnt(0)" ::: "memory");                   \
        }                                                                      \
        __builtin_amdgcn_sched_barrier(0);                                     \
        __builtin_amdgcn_s_barrier();       /* tile t landed for all waves */  \
        __builtin_amdgcn_sched_barrier(0);                                     \
        short8 afr[4], bfr[4];                                                 \
        _Pragma("unroll")                                                      \
        for (int q = 0; q < 4; ++q) {                                          \
            afr[q] = *(const short8*)(&Ash[d][aoff[q]]);                       \
            bfr[q] = *(const short8*)(&Bsh[d][boff[q]]);                       \
        }                                                                      \
        __builtin_amdgcn_s_setprio(1);                                         \
        _Pragma("unroll")                                                      \
        for (int mi = 0; mi < 4; ++mi)                                         \
            _Pragma("unroll")                                                  \
            for (int ni = 0; ni < 4; ++ni)                                     \
                acc[mi][ni] = __builtin_amdgcn_mfma_f32_16x16x32_bf16(         \
                    afr[mi], bfr[ni], acc[mi][ni], 0, 0, 0);                   \
        __builtin_amdgcn_s_setprio(0);                                         \
        __builtin_amdgcn_sched_barrier(0);                                     \
        __builtin_amdgcn_s_barrier();       /* all done reading buf d */       \
    } while (0)

    STG(0, 0);
    #pragma unroll 1
    for (int t = 0; t < NT; t += 2) {
        TILE(t, 0);
        TILE(t + 1, 1);
    }
#undef TILE
#undef STG

    // Epilogue: C/D col = lane&15, row = (lane>>4)*4 + reg
    #pragma unroll
    for (int ni = 0; ni < 4; ++ni) {
        const int col = v0 + wn * 64 + ni * 16 + (lane & 15);
        const float bv = bias[col];
        #pragma unroll
        for (int mi = 0; mi < 4; ++mi) {
            const int rbase = m0 + wm * 64 + mi * 16 + ((lane >> 4) << 2);
            #pragma unroll
            for (int reg = 0; reg < 4; ++reg) {
                out[(size_t)(rbase + reg) * VDIM + col] = acc[mi][ni][reg] + bv;
            }
        }
    }
}

// ---------------- fallback fused kernel (round-1 verified) ----------------
template <bool USE_WB>
__global__ __launch_bounds__(256) void joint_gemm_kernel(
    const float* __restrict__ f, const float* __restrict__ p,
    const float* __restrict__ Wf, const ushort* __restrict__ Wb,
    const float* __restrict__ bias, float* __restrict__ out)
{
    __shared__ ushort Alds[128 * 64];
    __shared__ ushort Blds[128 * 64];

    const int tid  = threadIdx.x;
    const int lane = tid & 63;
    const int wave = tid >> 6;
    const int wm   = wave >> 1;
    const int wn   = wave & 1;

    const int bid   = blockIdx.x;
    const int work  = (bid & 7) * 1024 + (bid >> 3);
    const int mtile = work >> 3;
    const int ntile = work & 7;
    const int m0 = mtile * 128;
    const int v0 = ntile * 128;

    const int b  = m0 >> 14;
    const int t0 = (m0 >> 6) & (TDIM - 1);

    const float*  fbase = f + (size_t)(b * TDIM + t0) * HDIM;
    const float*  pbase = p + (size_t)b * UDIM * HDIM;
    const ushort* wbbase = Wb + (size_t)v0 * HDIM;
    const float*  wfbase = Wf + (size_t)v0 * HDIM;

    f32x4 acc[4][4];
    #pragma unroll
    for (int i = 0; i < 4; ++i)
        #pragma unroll
        for (int j = 0; j < 4; ++j)
            acc[i][j] = (f32x4)0.0f;

    for (int kt = 0; kt < HDIM / 64; ++kt) {
        const int k0 = kt * 64;
        __syncthreads();

        if (USE_WB) {
            #pragma unroll
            for (int it = 0; it < 4; ++it) {
                const int c   = it * 256 + tid;
                const int row = c >> 3;
                const int j   = c & 7;
                const ushort* src = wbbase + row * HDIM + k0 + ((j ^ (row & 7)) << 3);
                GLDS(src, &Blds[(it * 256 + wave * 64) * 8]);
            }
        } else {
            #pragma unroll
            for (int it = 0; it < 4; ++it) {
                const int c   = it * 256 + tid;
                const int row = c >> 3;
                const int j   = c & 7;
                const float* wp = wfbase + row * HDIM + k0 + j * 8;
                f32x4 w0 = *(const f32x4*)wp;
                f32x4 w1 = *(const f32x4*)(wp + 4);
                short8 wv;
                #pragma unroll
                for (int e = 0; e < 4; ++e) {
                    wv[e]     = (short)f2bf(w0[e]);
                    wv[e + 4] = (short)f2bf(w1[e]);
                }
                *(short8*)(&Blds[(row * 8 + (j ^ (row & 7))) * 8]) = wv;
            }
        }

        #pragma unroll
        for (int it = 0; it < 4; ++it) {
            const int c   = it * 256 + tid;
            const int row = c >> 3;
            const int j   = c & 7;
            const float* fp_ = fbase + (row >> 6) * HDIM + k0 + j * 8;
            const float* pp_ = pbase + (row & 63) * HDIM + k0 + j * 8;
            f32x4 f0 = *(const f32x4*)fp_;
            f32x4 f1 = *(const f32x4*)(fp_ + 4);
            f32x4 p0 = *(const f32x4*)pp_;
            f32x4 p1 = *(const f32x4*)(pp_ + 4);
            short8 hv;
            #pragma unroll
            for (int e = 0; e < 4; ++e) {
                float a0 = fmaxf(f0[e] + p0[e], 0.0f);
                float a1 = fmaxf(f1[e] + p1[e], 0.0f);
                hv[e]     = (short)f2bf(a0);
                hv[e + 4] = (short)f2bf(a1);
            }
            *(short8*)(&Alds[(row * 8 + (j ^ (row & 7))) * 8]) = hv;
        }

        __syncthreads();

        #pragma unroll
        for (int ks = 0; ks < 2; ++ks) {
            short8 afr[4], bfr[4];
            #pragma unroll
            for (int mi = 0; mi < 4; ++mi) {
                const int r = wm * 64 + mi * 16 + (lane & 15);
                const int j = ks * 4 + (lane >> 4);
                afr[mi] = *(const short8*)(&Alds[(r * 8 + (j ^ (r & 7))) * 8]);
            }
            #pragma unroll
            for (int ni = 0; ni < 4; ++ni) {
                const int r = wn * 64 + ni * 16 + (lane & 15);
                const int j = ks * 4 + (lane >> 4);
                bfr[ni] = *(const short8*)(&Blds[(r * 8 + (j ^ (r & 7))) * 8]);
            }
            #pragma unroll
            for (int mi = 0; mi < 4; ++mi)
                #pragma unroll
                for (int ni = 0; ni < 4; ++ni)
                    acc[mi][ni] = __builtin_amdgcn_mfma_f32_16x16x32_bf16(
                        afr[mi], bfr[ni], acc[mi][ni], 0, 0, 0);
        }
    }

    #pragma unroll
    for (int ni = 0; ni < 4; ++ni) {
        const int col = v0 + wn * 64 + ni * 16 + (lane & 15);
        const float bv = bias[col];
        #pragma unroll
        for (int mi = 0; mi < 4; ++mi) {
            const int rbase = m0 + wm * 64 + mi * 16 + ((lane >> 4) << 2);
            #pragma unroll
            for (int reg = 0; reg < 4; ++reg) {
                out[(size_t)(rbase + reg) * VDIM + col] = acc[mi][ni][reg] + bv;
            }
        }
    }
}

extern "C" void kernel_launch(void* const* d_in, const int* in_sizes, int n_in,
                              void* d_out, int out_size, void* d_ws, size_t ws_size,
                              hipStream_t stream) {
    const float* f    = (const float*)d_in[0];   // (8,256,640)
    const float* p    = (const float*)d_in[1];   // (8,64,640)
    const float* W    = (const float*)d_in[2];   // (1024,640)
    const float* bias = (const float*)d_in[3];   // (1024)
    float* out = (float*)d_out;                  // (8,256,64,1024) fp32

    const size_t wb_bytes = (size_t)VDIM * HDIM * sizeof(ushort);   // 1.25 MB
    const size_t h_bytes  = (size_t)MDIM * HDIM * sizeof(ushort);   // 160 MB

    if (ws_size >= wb_bytes + h_bytes) {
        ushort* Wb = (ushort*)d_ws;
        ushort* h  = (ushort*)((char*)d_ws + wb_bytes);
        cvt_w_kernel<<<(VDIM * HDIM) / 1024, 256, 0, stream>>>(W, Wb);
        build_h_kernel<<<MDIM / 32, 256, 0, stream>>>(f, p, h);
        const int grid = (MDIM / BM) * (VDIM / BN);   // 8192
        hgemm128_kernel<<<grid, 256, 0, stream>>>(h, Wb, bias, out);
    } else if (ws_size >= wb_bytes) {
        ushort* Wb = (ushort*)d_ws;
        cvt_w_kernel<<<(VDIM * HDIM) / 1024, 256, 0, stream>>>(W, Wb);
        joint_gemm_kernel<true><<<(MDIM / 128) * (VDIM / 128), 256, 0, stream>>>(
            f, p, W, Wb, bias, out);
    } else {
        joint_gemm_kernel<false><<<(MDIM / 128) * (VDIM / 128), 256, 0, stream>>>(
            f, p, W, nullptr, bias, out);
    }
}